// Round 1
// baseline (799.855 us; speedup 1.0000x reference)
//
#include <hip/hip_runtime.h>

#define N_NODES 50000
#define IN_DIM 64
#define OUT_DIM 128
#define N_EDGES 800000

// ---------------- Phase 1: edge scatter (sum + count) ----------------
// 16 threads per edge; each thread handles one float4 (4 of 64 features).
__global__ __launch_bounds__(256) void sage_scatter(
    const float* __restrict__ x, const int* __restrict__ ei,
    float* __restrict__ summed, float* __restrict__ cnt)
{
    int gid = blockIdx.x * 256 + threadIdx.x;
    int e = gid >> 4;
    int q = gid & 15;
    if (e >= N_EDGES) return;
    int src = ei[e];
    int dst = ei[N_EDGES + e];
    const float4* xs = (const float4*)(x + (size_t)src * IN_DIM);
    float4 v = xs[q];
    float* srow = summed + (size_t)dst * IN_DIM + q * 4;
    atomicAdd(srow + 0, v.x);
    atomicAdd(srow + 1, v.y);
    atomicAdd(srow + 2, v.z);
    atomicAdd(srow + 3, v.w);
    if (q == 0) atomicAdd(cnt + dst, 1.0f);
}

// ---------------- Phase 2: fused linear ----------------
// out[n][o] = (summed[n]/max(cnt,1)) . Wl[o] + bl[o] + x[n] . Wr[o]
// Block = 256 threads: o = t&127, slot = t>>7 (2 nodes per block-iter).
// W rows live in VGPRs (unrolled); per-node rows are wave-uniform scalar loads.
__global__ __launch_bounds__(256) void sage_linear(
    const float* __restrict__ x, const float* __restrict__ summed,
    const float* __restrict__ cnt, const float* __restrict__ Wl,
    const float* __restrict__ bl, const float* __restrict__ Wr,
    float* __restrict__ out)
{
    int t = threadIdx.x;
    int o = t & 127;
    int slot = t >> 7;

    float4 wl[16], wr[16];
    const float4* wl4 = (const float4*)(Wl + (size_t)o * IN_DIM);
    const float4* wr4 = (const float4*)(Wr + (size_t)o * IN_DIM);
#pragma unroll
    for (int c = 0; c < 16; ++c) { wl[c] = wl4[c]; wr[c] = wr4[c]; }
    float bias = bl[o];

    const int npairs = N_NODES / 2;  // 50000 is even
    for (int p = blockIdx.x; p < npairs; p += gridDim.x) {
        int n = p * 2 + slot;
        n = __builtin_amdgcn_readfirstlane(n);  // wave-uniform -> s_load broadcasts
        const float4* xr = (const float4*)(x + (size_t)n * IN_DIM);
        const float4* sr = (const float4*)(summed + (size_t)n * IN_DIM);
        float accl = 0.f, accr = 0.f;
#pragma unroll
        for (int c = 0; c < 16; ++c) {
            float4 xc = xr[c];
            float4 sc = sr[c];
            accr = fmaf(xc.x, wr[c].x, accr);
            accr = fmaf(xc.y, wr[c].y, accr);
            accr = fmaf(xc.z, wr[c].z, accr);
            accr = fmaf(xc.w, wr[c].w, accr);
            accl = fmaf(sc.x, wl[c].x, accl);
            accl = fmaf(sc.y, wl[c].y, accl);
            accl = fmaf(sc.z, wl[c].z, accl);
            accl = fmaf(sc.w, wl[c].w, accl);
        }
        float cv = cnt[n];
        float inv = 1.0f / fmaxf(cv, 1.0f);
        out[(size_t)n * OUT_DIM + o] = fmaf(accl, inv, accr + bias);
    }
}

extern "C" void kernel_launch(void* const* d_in, const int* in_sizes, int n_in,
                              void* d_out, int out_size, void* d_ws, size_t ws_size,
                              hipStream_t stream) {
    const float* x  = (const float*)d_in[0];
    const int*   ei = (const int*)d_in[1];
    const float* Wl = (const float*)d_in[2];
    const float* bl = (const float*)d_in[3];
    const float* Wr = (const float*)d_in[4];
    float* out = (float*)d_out;

    float* summed = (float*)d_ws;                         // 50000*64 floats
    float* cnt    = summed + (size_t)N_NODES * IN_DIM;    // 50000 floats
    size_t zero_bytes = ((size_t)N_NODES * IN_DIM + N_NODES) * sizeof(float);

    hipMemsetAsync(d_ws, 0, zero_bytes, stream);

    int scatter_threads = N_EDGES * 16;
    int scatter_blocks = (scatter_threads + 255) / 256;   // = 50000 exactly
    sage_scatter<<<scatter_blocks, 256, 0, stream>>>(x, ei, summed, cnt);

    sage_linear<<<2048, 256, 0, stream>>>(x, summed, cnt, Wl, bl, Wr, out);
}

// Round 2
// 264.176 us; speedup vs baseline: 3.0277x; 3.0277x over previous
//
#include <hip/hip_runtime.h>

#define N_NODES 50000
#define IN_DIM 64
#define OUT_DIM 128
#define N_EDGES 800000

// ---------------- Phase 1: histogram of dst into offs (counts) ----------------
__global__ __launch_bounds__(256) void hist_k(const int* __restrict__ ei, int* __restrict__ offs)
{
    int e = blockIdx.x * 256 + threadIdx.x;
    if (e < N_EDGES) atomicAdd(&offs[ei[N_EDGES + e]], 1);
}

// ---------------- Phase 2: exclusive scan (counts -> starts), single workgroup ----------------
__global__ __launch_bounds__(1024) void scan_k(int* __restrict__ offs)
{
    __shared__ int wsum[16];
    __shared__ int carry_s;
    int t = threadIdx.x;
    int lane = t & 63, wid = t >> 6;
    if (t == 0) carry_s = 0;
    __syncthreads();
    for (int base = 0; base < N_NODES; base += 1024) {
        int i = base + t;
        int v = (i < N_NODES) ? offs[i] : 0;
        int incl = v;
#pragma unroll
        for (int d = 1; d < 64; d <<= 1) {
            int u = __shfl_up(incl, d, 64);
            if (lane >= d) incl += u;
        }
        if (lane == 63) wsum[wid] = incl;
        __syncthreads();                       // B1: wave sums ready
        if (wid == 0) {
            int s = (lane < 16) ? wsum[lane] : 0;
#pragma unroll
            for (int d = 1; d < 16; d <<= 1) {
                int u = __shfl_up(s, d, 64);
                if (lane >= d) s += u;
            }
            if (lane < 16) wsum[lane] = s;     // inclusive scan of wave sums
        }
        __syncthreads();                       // B2: scanned wave sums ready
        int waveoff = (wid > 0) ? wsum[wid - 1] : 0;
        int total = wsum[15];
        int carry = carry_s;
        int excl = carry + waveoff + incl - v;
        if (i < N_NODES) offs[i] = excl;
        __syncthreads();                       // B3: all reads of wsum/carry_s done
        if (t == 0) carry_s = carry + total;
        __syncthreads();                       // B4: carry updated for next chunk
    }
}

// ---------------- Phase 3: binning (starts -> ends as side effect) ----------------
__global__ __launch_bounds__(256) void bin_k(const int* __restrict__ ei,
                                             int* __restrict__ offs, int* __restrict__ srcs)
{
    int e = blockIdx.x * 256 + threadIdx.x;
    if (e < N_EDGES) {
        int dst = ei[N_EDGES + e];
        int pos = atomicAdd(&offs[dst], 1);
        srcs[pos] = ei[e];
    }
}

// ---------------- Phase 4: gather + mean (wave per node, lane = feature) ----------------
__global__ __launch_bounds__(256) void gather_k(const float* __restrict__ x,
                                                const int* __restrict__ offs,
                                                const int* __restrict__ srcs,
                                                float* __restrict__ mean)
{
    int gw = (blockIdx.x * 256 + threadIdx.x) >> 6;   // global wave id = node
    int lane = threadIdx.x & 63;
    if (gw >= N_NODES) return;
    int n = gw;
    int end = offs[n];                     // after binning: end(n)
    int start = n ? offs[n - 1] : 0;       // end(n-1) == start(n)
    float acc = 0.f;
    int j = start;
    while (j < end) {
        int m = end - j; if (m > 64) m = 64;
        int sv = (lane < m) ? srcs[j + lane] : 0;   // up to 64 indices in one load
        for (int k = 0; k < m; ++k) {
            int s = __shfl(sv, k, 64);
            acc += x[(size_t)s * IN_DIM + lane];
        }
        j += m;
    }
    int deg = end - start;
    float inv = deg ? 1.0f / (float)deg : 0.0f;
    mean[(size_t)n * IN_DIM + lane] = acc * inv;
}

// ---------------- Phase 5: fused linear ----------------
// out[n][o] = mean[n] . Wl[o] + bl[o] + x[n] . Wr[o]
__global__ __launch_bounds__(256) void sage_linear(
    const float* __restrict__ x, const float* __restrict__ mean,
    const float* __restrict__ Wl, const float* __restrict__ bl,
    const float* __restrict__ Wr, float* __restrict__ out)
{
    int t = threadIdx.x;
    int o = t & 127;
    int slot = t >> 7;

    float4 wl[16], wr[16];
    const float4* wl4 = (const float4*)(Wl + (size_t)o * IN_DIM);
    const float4* wr4 = (const float4*)(Wr + (size_t)o * IN_DIM);
#pragma unroll
    for (int c = 0; c < 16; ++c) { wl[c] = wl4[c]; wr[c] = wr4[c]; }
    float bias = bl[o];

    const int npairs = N_NODES / 2;
    for (int p = blockIdx.x; p < npairs; p += gridDim.x) {
        int n = p * 2 + slot;
        n = __builtin_amdgcn_readfirstlane(n);
        const float4* xr = (const float4*)(x + (size_t)n * IN_DIM);
        const float4* mr = (const float4*)(mean + (size_t)n * IN_DIM);
        float accl = 0.f, accr = 0.f;
#pragma unroll
        for (int c = 0; c < 16; ++c) {
            float4 xc = xr[c];
            float4 sc = mr[c];
            accr = fmaf(xc.x, wr[c].x, accr);
            accr = fmaf(xc.y, wr[c].y, accr);
            accr = fmaf(xc.z, wr[c].z, accr);
            accr = fmaf(xc.w, wr[c].w, accr);
            accl = fmaf(sc.x, wl[c].x, accl);
            accl = fmaf(sc.y, wl[c].y, accl);
            accl = fmaf(sc.z, wl[c].z, accl);
            accl = fmaf(sc.w, wl[c].w, accl);
        }
        out[(size_t)n * OUT_DIM + o] = accl + accr + bias;
    }
}

extern "C" void kernel_launch(void* const* d_in, const int* in_sizes, int n_in,
                              void* d_out, int out_size, void* d_ws, size_t ws_size,
                              hipStream_t stream) {
    const float* x  = (const float*)d_in[0];
    const int*   ei = (const int*)d_in[1];
    const float* Wl = (const float*)d_in[2];
    const float* bl = (const float*)d_in[3];
    const float* Wr = (const float*)d_in[4];
    float* out = (float*)d_out;

    // ws layout: offs[int x 50000] | srcs[int x 800000] | mean[float x 50000*64]
    int*   offs = (int*)d_ws;
    int*   srcs = offs + N_NODES;
    float* mean = (float*)(srcs + N_EDGES);

    hipMemsetAsync(offs, 0, (size_t)N_NODES * sizeof(int), stream);

    int eb = (N_EDGES + 255) / 256;                 // 3125
    hist_k<<<eb, 256, 0, stream>>>(ei, offs);
    scan_k<<<1, 1024, 0, stream>>>(offs);
    bin_k<<<eb, 256, 0, stream>>>(ei, offs, srcs);

    int gb = (N_NODES * 64 + 255) / 256;            // 12500
    gather_k<<<gb, 256, 0, stream>>>(x, offs, srcs, mean);

    sage_linear<<<2048, 256, 0, stream>>>(x, mean, Wl, bl, Wr, out);
}